// Round 12
// baseline (221.115 us; speedup 1.0000x reference)
//
#include <hip/hip_runtime.h>
#include <hip/hip_bf16.h>
#include <math.h>

#define S_LEN 2048
#define HID   2048
#define NH    32
#define NKV   8
#define HD    64
#define QKD   2560   // QK buffer row stride: Q[0:2048] | K[2048:2560]
#define LOG2E 1.44269504f
#define L2THETA_32 0.591611505f   // log2(500000)/32

typedef unsigned short u16;
typedef __attribute__((ext_vector_type(8))) short short8;   // 8 bf16 (MFMA A/B frag)
typedef __attribute__((ext_vector_type(4))) float f32x4;    // MFMA C/D frag

__device__ __forceinline__ u16 f2bf(float x) {
    union { __hip_bfloat16 b; u16 u; } c; c.b = __float2bfloat16(x); return c.u;
}
__device__ __forceinline__ float bf2f(u16 u) {
    union { unsigned int i; float f; } c; c.i = ((unsigned int)u) << 16; return c.f;
}
__device__ __forceinline__ void async_copy16(void* lds, const void* g) {
    __builtin_amdgcn_global_load_lds((const __attribute__((address_space(1))) unsigned int*)g,
                                     (__attribute__((address_space(3))) unsigned int*)lds,
                                     16, 0, 0);
}

// ---------------------------------------------------------------------------
// prep (R17 layout): cast_bf16 + ALL FOUR weight transposes in one dispatch.
// z 0..3 = transposes, z==4 = the X fp32->bf16 cast.
// ---------------------------------------------------------------------------
__global__ __launch_bounds__(256)
void prep(const float* __restrict__ X, u16* __restrict__ Xb,
          const float* __restrict__ Wq, const float* __restrict__ Wk,
          const float* __restrict__ Wv, const float* __restrict__ Wo,
          u16* __restrict__ WqkvT, u16* __restrict__ WoT) {
    if (blockIdx.z == 4) {
        // cast: 4.19M floats, 8 per thread; first 2048 of 4096 block slots
        const int i = (blockIdx.y * 64 + (int)blockIdx.x) * 256 + threadIdx.x;
        if (i >= 524288) return;
        const float4* p = (const float4*)(X + (size_t)i * 8);
        float4 a = p[0], b = p[1];
        short8 o;
        o[0] = f2bf(a.x); o[1] = f2bf(a.y); o[2] = f2bf(a.z); o[3] = f2bf(a.w);
        o[4] = f2bf(b.x); o[5] = f2bf(b.y); o[6] = f2bf(b.z); o[7] = f2bf(b.w);
        *(short8*)(Xb + (size_t)i * 8) = o;
        return;
    }
    const float* W; u16* WT; int Nin, xT;
    switch (blockIdx.z) {
        case 0:  W = Wq; WT = WqkvT;                         Nin = 2048; xT = 64; break;
        case 1:  W = Wk; WT = WqkvT + (size_t)2048 * 2048;   Nin = 512;  xT = 16; break;
        case 2:  W = Wv; WT = WqkvT + (size_t)2560 * 2048;   Nin = 512;  xT = 16; break;
        default: W = Wo; WT = WoT;                           Nin = 2048; xT = 64; break;
    }
    if ((int)blockIdx.x >= xT) return;
    __shared__ float tile[32][33];
    const int tx = threadIdx.x & 31, ty = threadIdx.x >> 5;
    const int x = blockIdx.x * 32 + tx;
#pragma unroll
    for (int j = ty; j < 32; j += 8)
        tile[j][tx] = W[(size_t)(blockIdx.y * 32 + j) * Nin + x];
    __syncthreads();
    const int xo = blockIdx.y * 32 + tx;
#pragma unroll
    for (int j = ty; j < 32; j += 8)
        WT[(size_t)(blockIdx.x * 32 + j) * 2048 + xo] = f2bf(tile[tx][j]);
}

// ---------------------------------------------------------------------------
// bf16 GEMM (R17-exact, best verified): 256 threads / 4 waves, 128x64 tile,
// BK=64, double-buffered LDS, conflict-free swizzled 128B rows (chunk^(row&7)
// pre-swizzled global source + fswz frag reads). Grids divide 256 CUs
// exactly: gemm<1> 48x16=768 (3.0/CU), gemm<0> 32x16=512 (2.0/CU).
// (R18/R19 NBUF=3 experiments netted zero vs this config — reverted.)
// MODE 0: fp32 C (stride N).
// MODE 1: QKV epilogue with FUSED RoPE (on fp32 acc before the bf16 round;
// Q cols also get 0.125*LOG2E). cols >= 2560 -> V TRANSPOSED to Vt[d][s].
// ---------------------------------------------------------------------------
template<int MODE>
__global__ __launch_bounds__(256)
void gemm_bt(const u16* __restrict__ A, const u16* __restrict__ Bt,
             void* __restrict__ Cv, u16* __restrict__ Vt,
             const int* __restrict__ pos, int M, int N, int K) {
    __shared__ __attribute__((aligned(16))) u16 As[2][8192];   // 2 x 16KB [128][128B]
    __shared__ __attribute__((aligned(16))) u16 Bs[2][4096];   // 2 x 8KB  [64][128B]
    const int t = threadIdx.x;           // 0..255
    const int lane = t & 63;
    const int w = t >> 6;                // 0..3
    const int lm = lane & 15, quad = lane >> 4;
    const int row0 = blockIdx.y * 128, col0 = blockIdx.x * 64;
    const int wr = w * 32;               // wave = 32 rows x 64 cols

    f32x4 acc[2][4];
#pragma unroll
    for (int i = 0; i < 2; ++i)
#pragma unroll
        for (int j = 0; j < 4; ++j) acc[i][j] = (f32x4){0.f, 0.f, 0.f, 0.f};

    const size_t strideB = (size_t)K * 2;
    const char* Ab = (const char*)(A + (size_t)row0 * K);
    const char* Bb = (const char*)(Bt + (size_t)col0 * K);

    // staging: thread t covers LDS rows {i*32 + t>>3}, chunk t&7 (8 x 16B
    // chunks per 128B row); source chunk pre-swizzled: (t&7) ^ (row&7)
    const int srow = t >> 3;                         // 0..31
    const int scswz = ((t & 7) ^ (srow & 7)) * 16;

    // one k-stage = 64 k: A 128x128B (4 ops) + B 64x128B (2 ops), uniform
    auto stage = [&](int ks, int buf) {
        const int k0b = ks * 128;        // byte offset along k
        char* ad = (char*)As[buf] + t * 16;
        char* bd = (char*)Bs[buf] + t * 16;
#pragma unroll
        for (int i = 0; i < 4; ++i)
            async_copy16(ad + i * 4096, Ab + (size_t)(i * 32 + srow) * strideB + k0b + scswz);
#pragma unroll
        for (int i = 0; i < 2; ++i)
            async_copy16(bd + i * 4096, Bb + (size_t)(i * 32 + srow) * strideB + k0b + scswz);
    };

    const int nk = K >> 6;
    stage(0, 0);
    if (nk > 1) stage(1, 1);

    const int fswz = (quad ^ (lm & 7)) << 4;

    for (int kk = 0; kk < nk; ++kk) {
        const int cur = kk & 1;
        // acquire: stage kk resident; stage kk+1 (6 ops) may stay in flight
        if (kk + 1 < nk) { asm volatile("s_waitcnt vmcnt(6)\ns_barrier" ::: "memory"); }
        else             { asm volatile("s_waitcnt vmcnt(0)\ns_barrier" ::: "memory"); }

        short8 af[2][2], bfv[4][2];
#pragma unroll
        for (int i = 0; i < 2; ++i) {
            const char* ar = (const char*)As[cur] + (wr + 16 * i + lm) * 128;
            af[i][0] = *(const short8*)(ar + fswz);
            af[i][1] = *(const short8*)(ar + (fswz ^ 64));
        }
#pragma unroll
        for (int j = 0; j < 4; ++j) {
            const char* br = (const char*)Bs[cur] + (16 * j + lm) * 128;
            bfv[j][0] = *(const short8*)(br + fswz);
            bfv[j][1] = *(const short8*)(br + (fswz ^ 64));
        }
#pragma unroll
        for (int i = 0; i < 2; ++i)
#pragma unroll
            for (int j = 0; j < 4; ++j) {
                acc[i][j] = __builtin_amdgcn_mfma_f32_16x16x32_bf16(af[i][0], bfv[j][0], acc[i][j], 0, 0, 0);
                acc[i][j] = __builtin_amdgcn_mfma_f32_16x16x32_bf16(af[i][1], bfv[j][1], acc[i][j], 0, 0, 0);
            }

        // release: frag reads drained -> safe to re-stage this buffer
        asm volatile("s_waitcnt lgkmcnt(0)\ns_barrier" ::: "memory");
        if (kk + 2 < nk) stage(kk + 2, cur);
    }

    // C/D layout: col = lane&15, row = quad*4 + reg  [m89-verified]
    const int cr = quad * 4;
    if (MODE == 0) {
#pragma unroll
        for (int i = 0; i < 2; ++i) {
            const int gr = row0 + wr + 16 * i + cr;
#pragma unroll
            for (int j = 0; j < 4; ++j) {
                const int gc = col0 + 16 * j + lm;
#pragma unroll
                for (int rr = 0; rr < 4; ++rr)
                    ((float*)Cv)[(size_t)(gr + rr) * N + gc] = acc[i][j][rr];
            }
        }
    } else if (col0 >= 2560) {
        // V written transposed to Vt[d][s]
#pragma unroll
        for (int i = 0; i < 2; ++i) {
            const int gr = row0 + wr + 16 * i + cr;
#pragma unroll
            for (int j = 0; j < 4; ++j) {
                const int d = col0 + 16 * j + lm - 2560;
                ushort4 vv;
                vv.x = f2bf(acc[i][j][0]); vv.y = f2bf(acc[i][j][1]);
                vv.z = f2bf(acc[i][j][2]); vv.w = f2bf(acc[i][j][3]);
                *(ushort4*)(Vt + (size_t)d * S_LEN + gr) = vv;
            }
        }
    } else {
        // Q/K cols: fused RoPE. Pair (d, d+32) = frags (j, j+2), same lane/
        // row. d = 16*jp + lm for jp in {0,1}. Q additionally scaled by
        // 0.125*log2e (log2-domain attention).
        const float qsc = (col0 < 2048) ? 0.125f * LOG2E : 1.0f;
        const float invf0 = exp2f(-(float)lm * L2THETA_32);          // d = lm
        const float invf1 = exp2f(-(float)(16 + lm) * L2THETA_32);   // d = 16+lm
#pragma unroll
        for (int i = 0; i < 2; ++i) {
            const int gr = row0 + wr + 16 * i + cr;
#pragma unroll
            for (int rr = 0; rr < 4; ++rr) {
                const float p = (float)pos[gr + rr];
                const float a0 = p * invf0, a1 = p * invf1;
                const float c0 = cosf(a0), s0 = sinf(a0);
                const float c1 = cosf(a1), s1 = sinf(a1);
                const float x00 = acc[i][0][rr], x02 = acc[i][2][rr];
                const float x01 = acc[i][1][rr], x03 = acc[i][3][rr];
                u16* outr = (u16*)Cv + (size_t)(gr + rr) * QKD + col0 + lm;
                outr[0]  = f2bf((x00 * c0 - x02 * s0) * qsc);
                outr[32] = f2bf((x02 * c0 + x00 * s0) * qsc);
                outr[16] = f2bf((x01 * c1 - x03 * s1) * qsc);
                outr[48] = f2bf((x03 * c1 + x01 * s1) * qsc);
            }
        }
    }
}

// ---------------------------------------------------------------------------
// MFMA flash attention (R20): CONCURRENCY rework. Diagnosis: attn (~41 us)
// is latency-bound with ~25% overlap efficiency — per-jt chain ~800cy
// crossing 2 barriers that couple 4 waves, and LDS (40KB) capped residency
// at the grid's 4 blocks/CU. New structure: q-tile 32, kv-tile 32, 2 waves
// (128 thr) per block, grid (64,32) = 2048 blocks. LDS = Q/P 4KB + K 2x4KB
// + V 2x4KB = 20KB -> 8 blocks/CU (8.0 exact). Per SIMD: 4 waves from 4
// INDEPENDENT blocks (barriers couple only 2 waves); chain halves.
// Layouts: K [32 kv][128B d] keeps chunk^(row&7) swizzle (fswz reads).
// V [64 d][64B kv] and P [32 q][64B kv] have 4-chunk rows: swizzle
// chunk^((row>>1)&3) (row&3 would alias banks every 4 rows at 64B stride;
// row>>1 gives 2-way = free). Same involution on stage-source and reads.
// Balanced qt: co-resident blocks (bx fixed, h = m+4j under the verified
// 256-periodic CU assignment) have u=h>>2 spanning 0..7 ->
// a=((bx>>3)+u)&7 spans 0..7, b=bx&7 fixed, qt=8a+(a&1?7-b:b):
// per-CU njt-sum = 260 EXACTLY; bijective per head.
// vmcnt: Q(2 ops) + 4/stage -> Q-wait vmcnt(8) (vmcnt(4) if njt==1),
// acquire vmcnt(4)/(0). Scores log2-domain, cap -16; row sums via ones MFMA.
// ---------------------------------------------------------------------------
__global__ __launch_bounds__(128)
void attn_mfma(const u16* __restrict__ QK, const u16* __restrict__ Vtg,
               u16* __restrict__ Ctx) {
    __shared__ __attribute__((aligned(16))) u16 QPs[2048];       // 4KB Q[32][128B]; P overlays [32][64B]
    __shared__ __attribute__((aligned(16))) u16 Ks[2][2048];     // 2 x 4KB [32 kv][128B d]
    __shared__ __attribute__((aligned(16))) u16 Vts[2][2048];    // 2 x 4KB [64 d][64B kv]

    const int t = threadIdx.x;           // 0..127
    const int lane = t & 63;
    const int w = t >> 6;                // 0..1
    const int lm = lane & 15, quad = lane >> 4;
    const int h = blockIdx.y;
    const int bx = blockIdx.x;           // 0..63
    // balanced qt (see header comment)
    const int a8 = ((bx >> 3) + (h >> 2)) & 7;
    const int b8 = bx & 7;
    const int qt = 8 * a8 + ((a8 & 1) ? 7 - b8 : b8);
    const int kh = h >> 2;
    const int q0 = qt * 32;
    const int njt = qt + 1;              // kv tiles of 32

    const char* Kb = (const char*)(QK + 2048 + kh * HD);
    const char* Vb = (const char*)(Vtg + (size_t)(kh * 64) * S_LEN);

    // staging swizzles (source pre-swizzled, LDS dest linear — rule 21)
    const int scswz = ((t & 7) ^ ((t >> 3) & 7)) * 16;   // K: 128B rows, row = t>>3 (+16)
    const int vswz  = ((t & 3) ^ ((t >> 3) & 3)) * 16;   // V: 64B rows, row = t>>2 (+32), (row>>1)&3 == (t>>3)&3

    // stage Q: wave w stages its own rows [w*16, w*16+16) (2 vm ops)
    {
        const char* qb = (const char*)(QK + h * HD);
        const int qrow = w * 16 + (lane >> 3);           // +k2*8; row&7 = lane>>3
        const int qcs = ((lane & 7) ^ (lane >> 3)) * 16;
#pragma unroll
        for (int k2 = 0; k2 < 2; ++k2)
            async_copy16((char*)QPs + w * 2048 + k2 * 1024 + lane * 16,
                         qb + (size_t)(q0 + qrow + k2 * 8) * (QKD * 2) + qcs);
    }

    auto stage_kv = [&](int jt_, int buf) {
        const int j0_ = jt_ * 32;
        char* kdst = (char*)Ks + buf * 4096 + t * 16;
        async_copy16(kdst,        Kb + (size_t)(j0_ + (t >> 3)) * (QKD * 2) + scswz);
        async_copy16(kdst + 2048, Kb + (size_t)(j0_ + 16 + (t >> 3)) * (QKD * 2) + scswz);
        char* vdst = (char*)Vts + buf * 4096 + t * 16;
        async_copy16(vdst,        Vb + (size_t)(t >> 2) * (S_LEN * 2) + j0_ * 2 + vswz);
        async_copy16(vdst + 2048, Vb + (size_t)(32 + (t >> 2)) * (S_LEN * 2) + j0_ * 2 + vswz);
    };

    stage_kv(0, 0);
    if (njt > 1) {
        stage_kv(1, 1);
        // Q (oldest 2 of 10) done; KV prefetches stay in flight
        asm volatile("s_waitcnt vmcnt(8)" ::: "memory");
    } else {
        // only Q(2) + kv0(4) outstanding -> Q done at vmcnt(4)
        asm volatile("s_waitcnt vmcnt(4)" ::: "memory");
    }

    // one-time Q fragment loads (B-operand: rows = q); swizzled read offset
    const int ra = w * 16 + lm;                      // ra&7 == lm&7
    const int fswz = (quad ^ (lm & 7)) << 4;         // 128B-row frag offset
    const int pvswz = (quad ^ ((lm >> 1) & 3)) << 4; // 64B-row frag offset
    const short8 qa0 = *(const short8*)((const char*)QPs + ra * 128 + fswz);
    const short8 qa1 = *(const short8*)((const char*)QPs + ra * 128 + (fswz ^ 64));
    // drain Q reads before P writes alias the region (wave-private rows)
    asm volatile("s_waitcnt lgkmcnt(0)" ::: "memory");

    // constant ones A-frag: row m=0 (lanes with lm==0) = 1.0
    short8 onesf;
    {
        const short ob = (lm == 0) ? (short)0x3F80 : (short)0;
#pragma unroll
        for (int j = 0; j < 8; ++j) onesf[j] = ob;
    }

    f32x4 oa[4], la;
#pragma unroll
    for (int dt = 0; dt < 4; ++dt) oa[dt] = (f32x4){0.f, 0.f, 0.f, 0.f};
    la = (f32x4){0.f, 0.f, 0.f, 0.f};

    const int plm2 = (lm >> 1) & 3;

    for (int jt = 0; jt < njt; ++jt) {
        const int cur = jt & 1;
        if (jt + 1 < njt) { asm volatile("s_waitcnt vmcnt(4)\ns_barrier" ::: "memory"); }
        else              { asm volatile("s_waitcnt vmcnt(0)\ns_barrier" ::: "memory"); }

        const char* Kc = (const char*)Ks + cur * 4096;
        const char* Vc = (const char*)Vts + cur * 4096;

        // S^T = K Q^T (32 kv x 16 q per wave... 2 ct tiles), log2, cap -16
        f32x4 sa[2];
#pragma unroll
        for (int ct = 0; ct < 2; ++ct)
            sa[ct] = (f32x4){-16.f, -16.f, -16.f, -16.f};
#pragma unroll
        for (int ct = 0; ct < 2; ++ct) {
            const char* kr = Kc + (ct * 16 + lm) * 128;
            short8 kf0 = *(const short8*)(kr + fswz);
            short8 kf1 = *(const short8*)(kr + (fswz ^ 64));
            sa[ct] = __builtin_amdgcn_mfma_f32_16x16x32_bf16(kf0, qa0, sa[ct], 0, 0, 0);
            sa[ct] = __builtin_amdgcn_mfma_f32_16x16x32_bf16(kf1, qa1, sa[ct], 0, 0, 0);
        }
        // causal mask: only the diagonal tile (jt == qt)
        if (jt == qt) {
#pragma unroll
            for (int ct = 0; ct < 2; ++ct) {
                const int kvl = ct * 16 + quad * 4;
#pragma unroll
                for (int r = 0; r < 4; ++r)
                    if (kvl + r > ra) sa[ct][r] = -1e30f;
            }
        }
        // p = exp2(s); pack 4 kv -> one b64 swizzled LDS write per ct
        // P row = 64B = 4 chunks, swizzle chunk^((row>>1)&3)
#pragma unroll
        for (int ct = 0; ct < 2; ++ct) {
            ushort4 pka;
            pka.x = f2bf(__builtin_amdgcn_exp2f(sa[ct][0]));
            pka.y = f2bf(__builtin_amdgcn_exp2f(sa[ct][1]));
            pka.z = f2bf(__builtin_amdgcn_exp2f(sa[ct][2]));
            pka.w = f2bf(__builtin_amdgcn_exp2f(sa[ct][3]));
            const int slot = (ct * 2 + (quad >> 1)) ^ plm2;
            *(ushort4*)((char*)QPs + ra * 64 + slot * 16 + ((quad & 1) << 3)) = pka;
        }
        // P frag (wave-private rows, in-order LDS pipe)
        const short8 pa = *(const short8*)((const char*)QPs + ra * 64 + pvswz);
        // O^T += V^T P^T; l += ones . P
#pragma unroll
        for (int dt = 0; dt < 4; ++dt) {
            short8 vf = *(const short8*)(Vc + (dt * 16 + lm) * 64 + pvswz);
            oa[dt] = __builtin_amdgcn_mfma_f32_16x16x32_bf16(vf, pa, oa[dt], 0, 0, 0);
        }
        la = __builtin_amdgcn_mfma_f32_16x16x32_bf16(onesf, pa, la, 0, 0, 0);

        // all waves done reading buf[cur] -> safe to prefetch jt+2 into it
        asm volatile("s_waitcnt lgkmcnt(0)\ns_barrier" ::: "memory");
        if (jt + 2 < njt) stage_kv(jt + 2, cur);
    }

    // l for q-row ra lives in lane lm (quad 0), reg 0 -> broadcast
    const float inva = 1.f / __shfl(la[0], lm);
    const int rowa = q0 + ra;
#pragma unroll
    for (int dt = 0; dt < 4; ++dt) {
        ushort4 o;
        o.x = f2bf(oa[dt][0] * inva); o.y = f2bf(oa[dt][1] * inva);
        o.z = f2bf(oa[dt][2] * inva); o.w = f2bf(oa[dt][3] * inva);
        *(ushort4*)(Ctx + (size_t)rowa * HID + h * HD + dt * 16 + quad * 4) = o;
    }
}

// ---------------------------------------------------------------------------
extern "C" void kernel_launch(void* const* d_in, const int* in_sizes, int n_in,
                              void* d_out, int out_size, void* d_ws, size_t ws_size,
                              hipStream_t stream) {
    const float* X   = (const float*)d_in[0];
    const int*   pos = (const int*)d_in[1];
    const float* Wq  = (const float*)d_in[2];
    const float* Wk  = (const float*)d_in[3];
    const float* Wv  = (const float*)d_in[4];
    const float* Wo  = (const float*)d_in[5];
    float* out = (float*)d_out;

    // ws (bf16 elems): Xb 4M | WqkvT 6M | WoT 4M | QK 5M | Vt 1M  ~= 42 MB
    u16* Xb    = (u16*)d_ws;
    u16* WqkvT = Xb + (size_t)4194304;
    u16* WoT   = WqkvT + (size_t)6291456;
    u16* QK    = WoT + (size_t)4194304;
    u16* Vt    = QK + (size_t)S_LEN * QKD;
    u16* Ctxb  = Xb;   // Xb dead after QKV GEMM

    prep<<<dim3(64, 64, 5), 256, 0, stream>>>(X, Xb, Wq, Wk, Wv, Wo, WqkvT, WoT);

    gemm_bt<1><<<dim3(48, 16), 256, 0, stream>>>(Xb, WqkvT, QK, Vt, pos, 2048, 3072, 2048);

    attn_mfma<<<dim3(64, 32), 128, 0, stream>>>(QK, Vt, Ctxb);

    gemm_bt<0><<<dim3(32, 16), 256, 0, stream>>>(Ctxb, WoT, out, nullptr, pos, 2048, 2048, 2048);
}

// Round 13
// 202.070 us; speedup vs baseline: 1.0942x; 1.0942x over previous
//
#include <hip/hip_runtime.h>
#include <hip/hip_bf16.h>
#include <math.h>

#define S_LEN 2048
#define HID   2048
#define NH    32
#define NKV   8
#define HD    64
#define QKD   2560   // QK buffer row stride: Q[0:2048] | K[2048:2560]
#define LOG2E 1.44269504f
#define L2THETA_32 0.591611505f   // log2(500000)/32

typedef unsigned short u16;
typedef __attribute__((ext_vector_type(8))) short short8;   // 8 bf16 (MFMA A/B frag)
typedef __attribute__((ext_vector_type(4))) float f32x4;    // MFMA C/D frag

__device__ __forceinline__ u16 f2bf(float x) {
    union { __hip_bfloat16 b; u16 u; } c; c.b = __float2bfloat16(x); return c.u;
}
__device__ __forceinline__ float bf2f(u16 u) {
    union { unsigned int i; float f; } c; c.i = ((unsigned int)u) << 16; return c.f;
}
__device__ __forceinline__ void async_copy16(void* lds, const void* g) {
    __builtin_amdgcn_global_load_lds((const __attribute__((address_space(1))) unsigned int*)g,
                                     (__attribute__((address_space(3))) unsigned int*)lds,
                                     16, 0, 0);
}

// ---------------------------------------------------------------------------
// prep (R21): cast + all four weight transposes; transpose inner loops
// VECTORIZED vs R17 — one float4 global read (row t>>3, 4 cols) and one
// ushort4 global store (out-row t>>3, 4 out-cols) per thread per tile,
// replacing 4 scalar loads + 4 scalar 2B stores. LDS tile [32][33] fp32:
// 33 = 1 mod 32 keeps both access phases <= 2-way bank aliasing.
// z 0..3 = transposes, z==4 = the X fp32->bf16 cast.
// ---------------------------------------------------------------------------
__global__ __launch_bounds__(256)
void prep(const float* __restrict__ X, u16* __restrict__ Xb,
          const float* __restrict__ Wq, const float* __restrict__ Wk,
          const float* __restrict__ Wv, const float* __restrict__ Wo,
          u16* __restrict__ WqkvT, u16* __restrict__ WoT) {
    if (blockIdx.z == 4) {
        // cast: 4.19M floats, 8 per thread; first 2048 of 4096 block slots
        const int i = (blockIdx.y * 64 + (int)blockIdx.x) * 256 + threadIdx.x;
        if (i >= 524288) return;
        const float4* p = (const float4*)(X + (size_t)i * 8);
        float4 a = p[0], b = p[1];
        short8 o;
        o[0] = f2bf(a.x); o[1] = f2bf(a.y); o[2] = f2bf(a.z); o[3] = f2bf(a.w);
        o[4] = f2bf(b.x); o[5] = f2bf(b.y); o[6] = f2bf(b.z); o[7] = f2bf(b.w);
        *(short8*)(Xb + (size_t)i * 8) = o;
        return;
    }
    const float* W; u16* WT; int Nin, xT;
    switch (blockIdx.z) {
        case 0:  W = Wq; WT = WqkvT;                         Nin = 2048; xT = 64; break;
        case 1:  W = Wk; WT = WqkvT + (size_t)2048 * 2048;   Nin = 512;  xT = 16; break;
        case 2:  W = Wv; WT = WqkvT + (size_t)2560 * 2048;   Nin = 512;  xT = 16; break;
        default: W = Wo; WT = WoT;                           Nin = 2048; xT = 64; break;
    }
    if ((int)blockIdx.x >= xT) return;
    __shared__ float tile[32][33];
    const int t = threadIdx.x;
    const int r8 = t >> 3;               // 0..31: row (read) / out-row (write)
    const int c4 = (t & 7) * 4;          // 4-col group
    // read: one float4 per thread — W[by*32 + r8][bx*32 + c4 .. +3]
    {
        const float4 v = *(const float4*)(W + (size_t)(blockIdx.y * 32 + r8) * Nin
                                            + blockIdx.x * 32 + c4);
        tile[r8][c4 + 0] = v.x; tile[r8][c4 + 1] = v.y;
        tile[r8][c4 + 2] = v.z; tile[r8][c4 + 3] = v.w;
    }
    __syncthreads();
    // write: one ushort4 per thread — WT[bx*32 + r8][by*32 + c4 .. +3]
    {
        ushort4 o;
        o.x = f2bf(tile[c4 + 0][r8]); o.y = f2bf(tile[c4 + 1][r8]);
        o.z = f2bf(tile[c4 + 2][r8]); o.w = f2bf(tile[c4 + 3][r8]);
        *(ushort4*)(WT + (size_t)(blockIdx.x * 32 + r8) * 2048
                       + blockIdx.y * 32 + c4) = o;
    }
}

// ---------------------------------------------------------------------------
// bf16 GEMM (R17-exact, best verified): 256 threads / 4 waves, 128x64 tile,
// BK=64, double-buffered LDS, conflict-free swizzled 128B rows (chunk^(row&7)
// pre-swizzled global source + fswz frag reads). Grids divide 256 CUs
// exactly: gemm<1> 48x16=768 (3.0/CU), gemm<0> 32x16=512 (2.0/CU).
// (R18/R19 NBUF=3 experiments netted zero — permanently reverted.)
// MODE 0: fp32 C (stride N).
// MODE 1: QKV epilogue with FUSED RoPE (on fp32 acc before the bf16 round;
// Q cols also get 0.125*LOG2E). cols >= 2560 -> V TRANSPOSED to Vt[d][s].
// ---------------------------------------------------------------------------
template<int MODE>
__global__ __launch_bounds__(256)
void gemm_bt(const u16* __restrict__ A, const u16* __restrict__ Bt,
             void* __restrict__ Cv, u16* __restrict__ Vt,
             const int* __restrict__ pos, int M, int N, int K) {
    __shared__ __attribute__((aligned(16))) u16 As[2][8192];   // 2 x 16KB [128][128B]
    __shared__ __attribute__((aligned(16))) u16 Bs[2][4096];   // 2 x 8KB  [64][128B]
    const int t = threadIdx.x;           // 0..255
    const int lane = t & 63;
    const int w = t >> 6;                // 0..3
    const int lm = lane & 15, quad = lane >> 4;
    const int row0 = blockIdx.y * 128, col0 = blockIdx.x * 64;
    const int wr = w * 32;               // wave = 32 rows x 64 cols

    f32x4 acc[2][4];
#pragma unroll
    for (int i = 0; i < 2; ++i)
#pragma unroll
        for (int j = 0; j < 4; ++j) acc[i][j] = (f32x4){0.f, 0.f, 0.f, 0.f};

    const size_t strideB = (size_t)K * 2;
    const char* Ab = (const char*)(A + (size_t)row0 * K);
    const char* Bb = (const char*)(Bt + (size_t)col0 * K);

    // staging: thread t covers LDS rows {i*32 + t>>3}, chunk t&7 (8 x 16B
    // chunks per 128B row); source chunk pre-swizzled: (t&7) ^ (row&7)
    const int srow = t >> 3;                         // 0..31
    const int scswz = ((t & 7) ^ (srow & 7)) * 16;

    // one k-stage = 64 k: A 128x128B (4 ops) + B 64x128B (2 ops), uniform
    auto stage = [&](int ks, int buf) {
        const int k0b = ks * 128;        // byte offset along k
        char* ad = (char*)As[buf] + t * 16;
        char* bd = (char*)Bs[buf] + t * 16;
#pragma unroll
        for (int i = 0; i < 4; ++i)
            async_copy16(ad + i * 4096, Ab + (size_t)(i * 32 + srow) * strideB + k0b + scswz);
#pragma unroll
        for (int i = 0; i < 2; ++i)
            async_copy16(bd + i * 4096, Bb + (size_t)(i * 32 + srow) * strideB + k0b + scswz);
    };

    const int nk = K >> 6;
    stage(0, 0);
    if (nk > 1) stage(1, 1);

    const int fswz = (quad ^ (lm & 7)) << 4;

    for (int kk = 0; kk < nk; ++kk) {
        const int cur = kk & 1;
        // acquire: stage kk resident; stage kk+1 (6 ops) may stay in flight
        if (kk + 1 < nk) { asm volatile("s_waitcnt vmcnt(6)\ns_barrier" ::: "memory"); }
        else             { asm volatile("s_waitcnt vmcnt(0)\ns_barrier" ::: "memory"); }

        short8 af[2][2], bfv[4][2];
#pragma unroll
        for (int i = 0; i < 2; ++i) {
            const char* ar = (const char*)As[cur] + (wr + 16 * i + lm) * 128;
            af[i][0] = *(const short8*)(ar + fswz);
            af[i][1] = *(const short8*)(ar + (fswz ^ 64));
        }
#pragma unroll
        for (int j = 0; j < 4; ++j) {
            const char* br = (const char*)Bs[cur] + (16 * j + lm) * 128;
            bfv[j][0] = *(const short8*)(br + fswz);
            bfv[j][1] = *(const short8*)(br + (fswz ^ 64));
        }
#pragma unroll
        for (int i = 0; i < 2; ++i)
#pragma unroll
            for (int j = 0; j < 4; ++j) {
                acc[i][j] = __builtin_amdgcn_mfma_f32_16x16x32_bf16(af[i][0], bfv[j][0], acc[i][j], 0, 0, 0);
                acc[i][j] = __builtin_amdgcn_mfma_f32_16x16x32_bf16(af[i][1], bfv[j][1], acc[i][j], 0, 0, 0);
            }

        // release: frag reads drained -> safe to re-stage this buffer
        asm volatile("s_waitcnt lgkmcnt(0)\ns_barrier" ::: "memory");
        if (kk + 2 < nk) stage(kk + 2, cur);
    }

    // C/D layout: col = lane&15, row = quad*4 + reg  [m89-verified]
    const int cr = quad * 4;
    if (MODE == 0) {
#pragma unroll
        for (int i = 0; i < 2; ++i) {
            const int gr = row0 + wr + 16 * i + cr;
#pragma unroll
            for (int j = 0; j < 4; ++j) {
                const int gc = col0 + 16 * j + lm;
#pragma unroll
                for (int rr = 0; rr < 4; ++rr)
                    ((float*)Cv)[(size_t)(gr + rr) * N + gc] = acc[i][j][rr];
            }
        }
    } else if (col0 >= 2560) {
        // V written transposed to Vt[d][s]
#pragma unroll
        for (int i = 0; i < 2; ++i) {
            const int gr = row0 + wr + 16 * i + cr;
#pragma unroll
            for (int j = 0; j < 4; ++j) {
                const int d = col0 + 16 * j + lm - 2560;
                ushort4 vv;
                vv.x = f2bf(acc[i][j][0]); vv.y = f2bf(acc[i][j][1]);
                vv.z = f2bf(acc[i][j][2]); vv.w = f2bf(acc[i][j][3]);
                *(ushort4*)(Vt + (size_t)d * S_LEN + gr) = vv;
            }
        }
    } else {
        // Q/K cols: fused RoPE. Pair (d, d+32) = frags (j, j+2), same lane/
        // row. d = 16*jp + lm for jp in {0,1}. Q additionally scaled by
        // 0.125*log2e (log2-domain attention).
        const float qsc = (col0 < 2048) ? 0.125f * LOG2E : 1.0f;
        const float invf0 = exp2f(-(float)lm * L2THETA_32);          // d = lm
        const float invf1 = exp2f(-(float)(16 + lm) * L2THETA_32);   // d = 16+lm
#pragma unroll
        for (int i = 0; i < 2; ++i) {
            const int gr = row0 + wr + 16 * i + cr;
#pragma unroll
            for (int rr = 0; rr < 4; ++rr) {
                const float p = (float)pos[gr + rr];
                const float a0 = p * invf0, a1 = p * invf1;
                const float c0 = cosf(a0), s0 = sinf(a0);
                const float c1 = cosf(a1), s1 = sinf(a1);
                const float x00 = acc[i][0][rr], x02 = acc[i][2][rr];
                const float x01 = acc[i][1][rr], x03 = acc[i][3][rr];
                u16* outr = (u16*)Cv + (size_t)(gr + rr) * QKD + col0 + lm;
                outr[0]  = f2bf((x00 * c0 - x02 * s0) * qsc);
                outr[32] = f2bf((x02 * c0 + x00 * s0) * qsc);
                outr[16] = f2bf((x01 * c1 - x03 * s1) * qsc);
                outr[48] = f2bf((x03 * c1 + x01 * s1) * qsc);
            }
        }
    }
}

// ---------------------------------------------------------------------------
// MFMA flash attention (R17-exact, best verified): Q-tile 64, grid (32,32),
// 4 waves x one 16-row q-group, balanced qt: b=(bx+h)&7, a=((bx>>3)+(h>>3))&3,
// qt = 8a + (a&1 ? 7-b : b) — co-resident quads get njt-sum == 66 exactly.
// (R20's 32x32/128-thr rework regressed — 2x restage+barrier count; reverted.)
// Swizzled conflict-free layouts (chunk^(row&7) pre-swizzled source; frag
// reads fswz/(fswz^64)). vmcnt: Q-wait vmcnt(8) (vmcnt(4) if njt==1),
// acquire vmcnt(4)/(0). Scores log2-domain, cap -16; row sums via ones MFMA.
// ---------------------------------------------------------------------------
__global__ __launch_bounds__(256)
void attn_mfma(const u16* __restrict__ QK, const u16* __restrict__ Vtg,
               u16* __restrict__ Ctx) {
    __shared__ __attribute__((aligned(16))) u16 QPs[4096];       // 8KB Q then P
    __shared__ __attribute__((aligned(16))) u16 Ks[2][4096];     // 2 x 8KB [64][128B]
    __shared__ __attribute__((aligned(16))) u16 Vts[2][4096];    // 2 x 8KB [64][128B]

    const int t = threadIdx.x;           // 0..255
    const int lane = t & 63;
    const int w = t >> 6;                // 0..3
    const int lm = lane & 15, quad = lane >> 4;
    const int h = blockIdx.y;
    // perfectly balanced qt (see header comment)
    const int b8 = ((int)blockIdx.x + h) & 7;
    const int a4 = (((int)blockIdx.x >> 3) + (h >> 3)) & 3;
    const int qt = 8 * a4 + ((a4 & 1) ? 7 - b8 : b8);
    const int kh = h >> 2;
    const int q0 = qt * 64;
    const int njt = qt + 1;                        // kv tiles of 64

    const char* Kb = (const char*)(QK + 2048 + kh * HD);
    const char* Vb = (const char*)(Vtg + (size_t)(kh * 64) * S_LEN);

    // staging: thread t covers LDS rows srow and srow+32, chunk t&7;
    // source chunk pre-swizzled: chunk' = (t&7) ^ (row&7), row&7 == srow&7
    const int srow = t >> 3;                         // 0..31
    const int scswz = ((t & 7) ^ (srow & 7)) * 16;

    // stage Q: wave w stages its own rows [w*16, w*16+16) (2 vm ops;
    // read-set == staged-set per wave -> per-wave vmcnt wait is sufficient)
    {
        const char* qb = (const char*)(QK + h * HD);
        const int qrow = w * 16 + (lane >> 3);       // + k2*8; row&7 = lane>>3
        const int qcs = ((lane & 7) ^ (lane >> 3)) * 16;
#pragma unroll
        for (int k2 = 0; k2 < 2; ++k2)
            async_copy16((char*)QPs + w * 2048 + k2 * 1024 + lane * 16,
                         qb + (size_t)(q0 + qrow + k2 * 8) * (QKD * 2) + qcs);
    }

    auto stage_kv = [&](int jt_, int buf) {
        const int j0_ = jt_ * 64;
        char* kdst = (char*)Ks + buf * 8192 + t * 16;
        char* vdst = (char*)Vts + buf * 8192 + t * 16;
        async_copy16(kdst,        Kb + (size_t)(j0_ + srow)      * (QKD * 2) + scswz);
        async_copy16(kdst + 4096, Kb + (size_t)(j0_ + 32 + srow) * (QKD * 2) + scswz);
        async_copy16(vdst,        Vb + (size_t)srow        * (S_LEN * 2) + j0_ * 2 + scswz);
        async_copy16(vdst + 4096, Vb + (size_t)(32 + srow) * (S_LEN * 2) + j0_ * 2 + scswz);
    };

    stage_kv(0, 0);
    if (njt > 1) {
        stage_kv(1, 1);
        // wait for this wave's Q (2 oldest of 10); KV prefetches in flight
        asm volatile("s_waitcnt vmcnt(8)" ::: "memory");
    } else {
        // only Q(2) + kv0(4) outstanding -> Q done at vmcnt(4)
        asm volatile("s_waitcnt vmcnt(4)" ::: "memory");
    }

    // one-time Q fragment loads (B-operand: rows = q); swizzled read offset
    const int ra = w * 16 + lm;                      // ra&7 == lm&7
    const int fswz = ((quad ^ (lm & 7)) << 4);
    const short8 qa0 = *(const short8*)((const char*)QPs + ra * 128 + fswz);
    const short8 qa1 = *(const short8*)((const char*)QPs + ra * 128 + (fswz ^ 64));
    // drain Q reads before P writes alias the region (wave-private rows)
    asm volatile("s_waitcnt lgkmcnt(0)" ::: "memory");

    // constant ones A-frag: row m=0 (lanes with lm==0) = 1.0
    short8 onesf;
    {
        const short ob = (lm == 0) ? (short)0x3F80 : (short)0;
#pragma unroll
        for (int j = 0; j < 8; ++j) onesf[j] = ob;
    }

    f32x4 oa[4], la;
#pragma unroll
    for (int dt = 0; dt < 4; ++dt) oa[dt] = (f32x4){0.f, 0.f, 0.f, 0.f};
    la = (f32x4){0.f, 0.f, 0.f, 0.f};

    for (int jt = 0; jt < njt; ++jt) {
        const int cur = jt & 1;
        if (jt + 1 < njt) { asm volatile("s_waitcnt vmcnt(4)\ns_barrier" ::: "memory"); }
        else              { asm volatile("s_waitcnt vmcnt(0)\ns_barrier" ::: "memory"); }

        const char* Kc = (const char*)Ks + cur * 8192;
        const char* Vc = (const char*)Vts + cur * 8192;

        // S^T = K Q^T, log2 domain, cap -16
        f32x4 sa[4];
#pragma unroll
        for (int ct = 0; ct < 4; ++ct)
            sa[ct] = (f32x4){-16.f, -16.f, -16.f, -16.f};
#pragma unroll
        for (int ct = 0; ct < 4; ++ct) {
            const char* kr = Kc + (ct * 16 + lm) * 128;
            short8 kf0 = *(const short8*)(kr + fswz);
            short8 kf1 = *(const short8*)(kr + (fswz ^ 64));
            sa[ct] = __builtin_amdgcn_mfma_f32_16x16x32_bf16(kf0, qa0, sa[ct], 0, 0, 0);
            sa[ct] = __builtin_amdgcn_mfma_f32_16x16x32_bf16(kf1, qa1, sa[ct], 0, 0, 0);
        }
        // causal mask: only the diagonal tile (jt == qt)
        if (jt == qt) {
#pragma unroll
            for (int ct = 0; ct < 4; ++ct) {
                const int kvl = ct * 16 + quad * 4;
#pragma unroll
                for (int r = 0; r < 4; ++r)
                    if (kvl + r > ra) sa[ct][r] = -1e30f;
            }
        }
        // p = exp2(s); pack 4 kv -> one b64 swizzled LDS write per ct
#pragma unroll
        for (int ct = 0; ct < 4; ++ct) {
            ushort4 pka;
            pka.x = f2bf(__builtin_amdgcn_exp2f(sa[ct][0]));
            pka.y = f2bf(__builtin_amdgcn_exp2f(sa[ct][1]));
            pka.z = f2bf(__builtin_amdgcn_exp2f(sa[ct][2]));
            pka.w = f2bf(__builtin_amdgcn_exp2f(sa[ct][3]));
            const int pc = (((2 * ct + (quad >> 1)) ^ (lm & 7)) << 4) + ((quad & 1) << 3);
            *(ushort4*)((char*)QPs + ra * 128 + pc) = pka;
        }
        // P frags (wave-private rows, in-order LDS pipe); same fswz pattern
        const short8 pa0 = *(const short8*)((const char*)QPs + ra * 128 + fswz);
        const short8 pa1 = *(const short8*)((const char*)QPs + ra * 128 + (fswz ^ 64));
        // O^T += V^T P^T; l += ones . P
#pragma unroll
        for (int dt = 0; dt < 4; ++dt) {
            const char* vr = Vc + (dt * 16 + lm) * 128;
            short8 vf0 = *(const short8*)(vr + fswz);
            short8 vf1 = *(const short8*)(vr + (fswz ^ 64));
            oa[dt] = __builtin_amdgcn_mfma_f32_16x16x32_bf16(vf0, pa0, oa[dt], 0, 0, 0);
            oa[dt] = __builtin_amdgcn_mfma_f32_16x16x32_bf16(vf1, pa1, oa[dt], 0, 0, 0);
        }
        la = __builtin_amdgcn_mfma_f32_16x16x32_bf16(onesf, pa0, la, 0, 0, 0);
        la = __builtin_amdgcn_mfma_f32_16x16x32_bf16(onesf, pa1, la, 0, 0, 0);

        // all waves done reading buf[cur] -> safe to prefetch jt+2 into it
        asm volatile("s_waitcnt lgkmcnt(0)\ns_barrier" ::: "memory");
        if (jt + 2 < njt) stage_kv(jt + 2, cur);
    }

    // l for q-row ra lives in lane lm (quad 0), reg 0 -> broadcast
    const float inva = 1.f / __shfl(la[0], lm);
    const int rowa = q0 + ra;
#pragma unroll
    for (int dt = 0; dt < 4; ++dt) {
        ushort4 o;
        o.x = f2bf(oa[dt][0] * inva); o.y = f2bf(oa[dt][1] * inva);
        o.z = f2bf(oa[dt][2] * inva); o.w = f2bf(oa[dt][3] * inva);
        *(ushort4*)(Ctx + (size_t)rowa * HID + h * HD + dt * 16 + quad * 4) = o;
    }
}

// ---------------------------------------------------------------------------
extern "C" void kernel_launch(void* const* d_in, const int* in_sizes, int n_in,
                              void* d_out, int out_size, void* d_ws, size_t ws_size,
                              hipStream_t stream) {
    const float* X   = (const float*)d_in[0];
    const int*   pos = (const int*)d_in[1];
    const float* Wq  = (const float*)d_in[2];
    const float* Wk  = (const float*)d_in[3];
    const float* Wv  = (const float*)d_in[4];
    const float* Wo  = (const float*)d_in[5];
    float* out = (float*)d_out;

    // ws (bf16 elems): Xb 4M | WqkvT 6M | WoT 4M | QK 5M | Vt 1M  ~= 42 MB
    u16* Xb    = (u16*)d_ws;
    u16* WqkvT = Xb + (size_t)4194304;
    u16* WoT   = WqkvT + (size_t)6291456;
    u16* QK    = WoT + (size_t)4194304;
    u16* Vt    = QK + (size_t)S_LEN * QKD;
    u16* Ctxb  = Xb;   // Xb dead after QKV GEMM

    prep<<<dim3(64, 64, 5), 256, 0, stream>>>(X, Xb, Wq, Wk, Wv, Wo, WqkvT, WoT);

    gemm_bt<1><<<dim3(48, 16), 256, 0, stream>>>(Xb, WqkvT, QK, Vt, pos, 2048, 3072, 2048);

    attn_mfma<<<dim3(32, 32), 256, 0, stream>>>(QK, Vt, Ctxb);

    gemm_bt<0><<<dim3(32, 16), 256, 0, stream>>>(Ctxb, WoT, out, nullptr, pos, 2048, 2048, 2048);
}